// Round 1
// baseline (356.735 us; speedup 1.0000x reference)
//
#include <hip/hip_runtime.h>
#include <hip/hip_bf16.h>

// ---------------------------------------------------------------------------
// MultiHeadAttention: B=2, S=2048, D=1024, H=16, dh=64 (fp32 in/out)
// Pipeline (all intermediates bf16 in d_ws, fp32 accumulation):
//   1) X -> bf16 (queries/keys/values)
//   2) W -> bf16 transposed (Wt[N][K]) so GEMM B-operand reads K-contiguous
//   3) Q=Xq@Wq, K=Xk@Wk, V=Xv@Wv   (bf16 MFMA GEMM, 128x128 tile)
//   4) V -> Vt (per-column-major) for PV B-operand
//   5) flash attention per (b,h), q-tile=64 rows, kv-tile=64
//   6) out = Y @ Wo (fp32 output)
// ---------------------------------------------------------------------------

typedef __attribute__((ext_vector_type(8))) short bf16x8;   // 8 bf16 = 4 VGPRs
typedef __attribute__((ext_vector_type(4))) float f32x4;

__device__ __forceinline__ unsigned short f2b(float f) {
    // round-to-nearest-even fp32 -> bf16
    unsigned int u = __float_as_uint(f);
    u += 0x7FFFu + ((u >> 16) & 1u);
    return (unsigned short)(u >> 16);
}

__device__ __forceinline__ void gld_lds16(const void* g, void* l) {
    // async global->LDS, 16B per lane; LDS dest = wave-uniform base + lane*16
    __builtin_amdgcn_global_load_lds(
        (const __attribute__((address_space(1))) unsigned int*)g,
        (__attribute__((address_space(3))) unsigned int*)l,
        16, 0, 0);
}

// ---------------------------------------------------------------------------
// elementwise fp32 -> bf16 (vectorized float4 -> 4x bf16)
// ---------------------------------------------------------------------------
__global__ __launch_bounds__(256) void f32_to_bf16_vec(
    const float* __restrict__ in, unsigned short* __restrict__ out, int n4)
{
    int i = blockIdx.x * 256 + threadIdx.x;
    if (i < n4) {
        float4 v = ((const float4*)in)[i];
        ushort4 o;
        o.x = f2b(v.x); o.y = f2b(v.y); o.z = f2b(v.z); o.w = f2b(v.w);
        ((ushort4*)out)[i] = o;
    }
}

// ---------------------------------------------------------------------------
// transpose (+ optional fp32->bf16 convert): out[c][r] = cvt(in[r][c])
// in: [R][C], out: [C][R]. R,C multiples of 32. block (32,8)
// ---------------------------------------------------------------------------
template <typename TIN>
__global__ __launch_bounds__(256) void transpose_bf16(
    const TIN* __restrict__ in, unsigned short* __restrict__ out, int R, int C)
{
    __shared__ unsigned short tile[32][33];   // +1 pad: no bank conflicts
    const int c0 = blockIdx.x * 32, r0 = blockIdx.y * 32;
    const int tx = threadIdx.x, ty = threadIdx.y;
#pragma unroll
    for (int i = 0; i < 4; ++i) {
        TIN v = in[(size_t)(r0 + ty + i * 8) * C + c0 + tx];
        if constexpr (sizeof(TIN) == 4)
            tile[ty + i * 8][tx] = f2b((float)v);
        else
            tile[ty + i * 8][tx] = (unsigned short)v;
    }
    __syncthreads();
#pragma unroll
    for (int i = 0; i < 4; ++i)
        out[(size_t)(c0 + ty + i * 8) * R + r0 + tx] = tile[tx][ty + i * 8];
}

// ---------------------------------------------------------------------------
// GEMM: C[M][N] = A[M][K] * Bt[N][K]^T   (A,Bt bf16; C bf16 or fp32)
// 128x128 tile, BK=32, 4 waves (2x2), each wave 64x64 = 4x4 16x16x32 MFMA
// ---------------------------------------------------------------------------
template <typename TOUT>
__global__ __launch_bounds__(256) void gemm_bt(
    const unsigned short* __restrict__ A,
    const unsigned short* __restrict__ Bt,
    TOUT* __restrict__ C, int M, int N, int K)
{
    __shared__ unsigned short lds_a[128 * 32];
    __shared__ unsigned short lds_b[128 * 32];
    const int tid = threadIdx.x;
    const int wid = tid >> 6;
    const int ln  = tid & 15;          // lane & 15
    const int lg  = (tid & 63) >> 4;   // lane >> 4
    const int m0 = blockIdx.y * 128, n0 = blockIdx.x * 128;
    const int wr = wid >> 1, wc = wid & 1;

    const f32x4 fz = {0.f, 0.f, 0.f, 0.f};
    f32x4 acc[4][4];
#pragma unroll
    for (int m = 0; m < 4; ++m)
#pragma unroll
        for (int n = 0; n < 4; ++n) acc[m][n] = fz;

    // staging: thread t covers LDS elems (t + j*256)*8 .. +8
    //   row = t/4 + j*64, col = (t%4)*8   of the [128][32] tile (linear)
    const int srow = tid >> 2, scol = (tid & 3) * 8;
    const unsigned short* ga = A  + (size_t)(m0 + srow) * K + scol;
    const unsigned short* gb = Bt + (size_t)(n0 + srow) * K + scol;
    unsigned short* la = &lds_a[wid * 512];   // wave-uniform LDS base
    unsigned short* lb = &lds_b[wid * 512];

    for (int k0 = 0; k0 < K; k0 += 32) {
        gld_lds16(ga + k0,                 la);
        gld_lds16(ga + k0 + (size_t)64 * K, la + 2048);
        gld_lds16(gb + k0,                 lb);
        gld_lds16(gb + k0 + (size_t)64 * K, lb + 2048);
        __syncthreads();   // drains vmcnt -> tiles visible

        bf16x8 af[4], bfr[4];
#pragma unroll
        for (int m = 0; m < 4; ++m)
            af[m] = *(const bf16x8*)&lds_a[(wr * 64 + m * 16 + ln) * 32 + lg * 8];
#pragma unroll
        for (int n = 0; n < 4; ++n)
            bfr[n] = *(const bf16x8*)&lds_b[(wc * 64 + n * 16 + ln) * 32 + lg * 8];
#pragma unroll
        for (int m = 0; m < 4; ++m)
#pragma unroll
            for (int n = 0; n < 4; ++n)
                acc[m][n] = __builtin_amdgcn_mfma_f32_16x16x32_bf16(
                    af[m], bfr[n], acc[m][n], 0, 0, 0);
        __syncthreads();   // compute done before next-tile overwrite
    }

    // C/D layout: col = lane&15, row = (lane>>4)*4 + reg
#pragma unroll
    for (int m = 0; m < 4; ++m)
#pragma unroll
        for (int n = 0; n < 4; ++n)
#pragma unroll
            for (int r = 0; r < 4; ++r) {
                int gr = m0 + wr * 64 + m * 16 + lg * 4 + r;
                int gc = n0 + wc * 64 + n * 16 + ln;
                if constexpr (sizeof(TOUT) == 2)
                    C[(size_t)gr * N + gc] = (TOUT)f2b(acc[m][n][r]);
                else
                    C[(size_t)gr * N + gc] = (TOUT)acc[m][n][r];
            }
}

// ---------------------------------------------------------------------------
// flash attention: one block = 64 q-rows of one (b,h); 4 waves x 16 q-rows
// Q[4096][1024], K[4096][1024] (head at cols h*64..), Vt[1024][4096]
// ---------------------------------------------------------------------------
__global__ __launch_bounds__(256) void attn_kernel(
    const unsigned short* __restrict__ Q,
    const unsigned short* __restrict__ Km,
    const unsigned short* __restrict__ Vt,
    unsigned short* __restrict__ Y)
{
    constexpr int D = 1024, S = 2048, HD = 64;
    __shared__ unsigned short lds_k[64 * 72];      // [kv][d], +8 pad
    __shared__ unsigned short lds_v[64 * 72];      // [d][kv], +8 pad
    __shared__ unsigned short lds_p[4][16 * 72];   // per-wave P tile

    const int tid = threadIdx.x;
    const int wid = tid >> 6;
    const int ln  = tid & 15;
    const int lg  = (tid & 63) >> 4;
    const int b = blockIdx.y >> 4, h = blockIdx.y & 15;
    const int tok0 = b * S;
    const int q0 = blockIdx.x * 64 + wid * 16;

    // Q A-fragments: row = ln, k(d) = lg*8 + i (+32 for frag 1)
    const unsigned short* qrow = Q + (size_t)(tok0 + q0 + ln) * D + h * HD;
    bf16x8 qa0 = *(const bf16x8*)(qrow + lg * 8);
    bf16x8 qa1 = *(const bf16x8*)(qrow + 32 + lg * 8);

    const f32x4 fz = {0.f, 0.f, 0.f, 0.f};
    float m_run[4], l_run[4];
    f32x4 o[4];
#pragma unroll
    for (int r = 0; r < 4; ++r) { m_run[r] = -1e30f; l_run[r] = 0.f; }
#pragma unroll
    for (int db = 0; db < 4; ++db) o[db] = fz;

    const int stg_r = tid >> 3;          // 0..31
    const int stg_c = (tid & 7) * 8;     // 0..56
    const unsigned short* gk = Km + (size_t)tok0 * D + h * HD;
    const unsigned short* gv = Vt + (size_t)(h * HD) * 4096 + tok0;

    for (int kv0 = 0; kv0 < S; kv0 += 64) {
        __syncthreads();   // previous iteration's reads done
        // stage K tile [64][64] and Vt tile [64][64] (reg->LDS, padded rows)
#pragma unroll
        for (int j = 0; j < 2; ++j) {
            int r = stg_r + j * 32;
            bf16x8 kvv = *(const bf16x8*)(gk + (size_t)(kv0 + r) * D + stg_c);
            *(bf16x8*)&lds_k[r * 72 + stg_c] = kvv;
            bf16x8 vvv = *(const bf16x8*)(gv + (size_t)r * 4096 + kv0 + stg_c);
            *(bf16x8*)&lds_v[r * 72 + stg_c] = vvv;
        }
        __syncthreads();

        // scores: S[q][kv] = sum_d Q[q][d] K[kv][d]; B-frag col=kv -> K rows
        f32x4 s[4];
#pragma unroll
        for (int n = 0; n < 4; ++n) {
            bf16x8 kb0 = *(const bf16x8*)&lds_k[(n * 16 + ln) * 72 + lg * 8];
            bf16x8 kb1 = *(const bf16x8*)&lds_k[(n * 16 + ln) * 72 + 32 + lg * 8];
            f32x4 z = fz;
            z = __builtin_amdgcn_mfma_f32_16x16x32_bf16(qa0, kb0, z, 0, 0, 0);
            z = __builtin_amdgcn_mfma_f32_16x16x32_bf16(qa1, kb1, z, 0, 0, 0);
            s[n] = z * 0.125f;   // 1/sqrt(dh)
        }

        // online softmax over this kv-block (rows = lg*4 + r)
        float pm[4];
#pragma unroll
        for (int r = 0; r < 4; ++r)
            pm[r] = fmaxf(fmaxf(s[0][r], s[1][r]), fmaxf(s[2][r], s[3][r]));
#pragma unroll
        for (int mask = 1; mask <= 8; mask <<= 1)
#pragma unroll
            for (int r = 0; r < 4; ++r)
                pm[r] = fmaxf(pm[r], __shfl_xor(pm[r], mask));

        float alpha[4];
#pragma unroll
        for (int r = 0; r < 4; ++r) {
            float mn = fmaxf(m_run[r], pm[r]);
            alpha[r] = __expf(m_run[r] - mn);
            m_run[r] = mn;
        }

        float rs[4] = {0.f, 0.f, 0.f, 0.f};
#pragma unroll
        for (int n = 0; n < 4; ++n)
#pragma unroll
            for (int r = 0; r < 4; ++r) {
                float p = __expf(s[n][r] - m_run[r]);
                rs[r] += p;
                lds_p[wid][(lg * 4 + r) * 72 + n * 16 + ln] = f2b(p);
            }
#pragma unroll
        for (int mask = 1; mask <= 8; mask <<= 1)
#pragma unroll
            for (int r = 0; r < 4; ++r) rs[r] += __shfl_xor(rs[r], mask);

        f32x4 av;
#pragma unroll
        for (int r = 0; r < 4; ++r) {
            l_run[r] = l_run[r] * alpha[r] + rs[r];
            av[r] = alpha[r];
        }
#pragma unroll
        for (int db = 0; db < 4; ++db) o[db] *= av;

        // PV: A-frag = P (row=ln, k=kv), B-frag = Vt rows (col=d=ln)
        bf16x8 pa0 = *(const bf16x8*)&lds_p[wid][ln * 72 + lg * 8];
        bf16x8 pa1 = *(const bf16x8*)&lds_p[wid][ln * 72 + 32 + lg * 8];
#pragma unroll
        for (int db = 0; db < 4; ++db) {
            bf16x8 vb0 = *(const bf16x8*)&lds_v[(db * 16 + ln) * 72 + lg * 8];
            bf16x8 vb1 = *(const bf16x8*)&lds_v[(db * 16 + ln) * 72 + 32 + lg * 8];
            o[db] = __builtin_amdgcn_mfma_f32_16x16x32_bf16(pa0, vb0, o[db], 0, 0, 0);
            o[db] = __builtin_amdgcn_mfma_f32_16x16x32_bf16(pa1, vb1, o[db], 0, 0, 0);
        }
    }

    // epilogue: rows = lg*4 + r, cols = db*16 + ln
#pragma unroll
    for (int db = 0; db < 4; ++db)
#pragma unroll
        for (int r = 0; r < 4; ++r) {
            float val = o[db][r] / l_run[r];
            Y[(size_t)(tok0 + q0 + lg * 4 + r) * D + h * HD + db * 16 + ln] = f2b(val);
        }
}

// ---------------------------------------------------------------------------
extern "C" void kernel_launch(void* const* d_in, const int* in_sizes, int n_in,
                              void* d_out, int out_size, void* d_ws, size_t ws_size,
                              hipStream_t stream)
{
    const float* q_f = (const float*)d_in[0];
    const float* k_f = (const float*)d_in[1];
    const float* v_f = (const float*)d_in[2];
    const float* Wq  = (const float*)d_in[3];
    const float* Wk  = (const float*)d_in[4];
    const float* Wv  = (const float*)d_in[5];
    const float* Wo  = (const float*)d_in[6];
    float* out = (float*)d_out;

    const int BS = 4096, D = 1024;          // B*S rows, model dim
    const size_t X = (size_t)BS * D;        // elems
    const size_t W = (size_t)D * D;

    unsigned short* ws  = (unsigned short*)d_ws;
    unsigned short* qb  = ws;
    unsigned short* kb  = qb  + X;
    unsigned short* vb  = kb  + X;
    unsigned short* wqt = vb  + X;
    unsigned short* wkt = wqt + W;
    unsigned short* wvt = wkt + W;
    unsigned short* wot = wvt + W;
    unsigned short* Qp  = wot + W;
    unsigned short* Kp  = Qp  + X;
    unsigned short* Vp  = Kp  + X;
    unsigned short* Vtp = Vp  + X;
    unsigned short* Yb  = Vtp + X;

    // 1) inputs -> bf16
    int n4 = (int)(X / 4);
    f32_to_bf16_vec<<<(n4 + 255) / 256, 256, 0, stream>>>(q_f, qb, n4);
    f32_to_bf16_vec<<<(n4 + 255) / 256, 256, 0, stream>>>(k_f, kb, n4);
    f32_to_bf16_vec<<<(n4 + 255) / 256, 256, 0, stream>>>(v_f, vb, n4);

    // 2) weights -> bf16 transposed
    dim3 tb(32, 8);
    transpose_bf16<float><<<dim3(32, 32), tb, 0, stream>>>(Wq, wqt, D, D);
    transpose_bf16<float><<<dim3(32, 32), tb, 0, stream>>>(Wk, wkt, D, D);
    transpose_bf16<float><<<dim3(32, 32), tb, 0, stream>>>(Wv, wvt, D, D);
    transpose_bf16<float><<<dim3(32, 32), tb, 0, stream>>>(Wo, wot, D, D);

    // 3) projections
    dim3 gg(D / 128, BS / 128);   // (8, 32)
    gemm_bt<unsigned short><<<gg, 256, 0, stream>>>(qb, wqt, Qp, BS, D, D);
    gemm_bt<unsigned short><<<gg, 256, 0, stream>>>(kb, wkt, Kp, BS, D, D);
    gemm_bt<unsigned short><<<gg, 256, 0, stream>>>(vb, wvt, Vp, BS, D, D);

    // 4) V -> Vt [1024][4096]
    transpose_bf16<unsigned short><<<dim3(D / 32, BS / 32), tb, 0, stream>>>(Vp, Vtp, BS, D);

    // 5) attention
    attn_kernel<<<dim3(2048 / 64, 32), 256, 0, stream>>>(Qp, Kp, Vtp, Yb);

    // 6) output projection (fp32 out)
    gemm_bt<float><<<gg, 256, 0, stream>>>(Yb, wot, out, BS, D, D);
}

// Round 4
// 249.900 us; speedup vs baseline: 1.4275x; 1.4275x over previous
//
#include <hip/hip_runtime.h>
#include <hip/hip_bf16.h>

// ---------------------------------------------------------------------------
// MHA B=2,S=2048,D=1024,H=16,dh=64 (fp32 in/out), bf16 MFMA pipeline.
// R3 = R2 with the PV MFMA operand order fixed: O^T = Vt x P^T requires
// A = V-fragment (rows = d), B = P-fragment (cols = q). R2 had (P, V),
// which transposed the per-lane accumulator orientation and broke the
// per-lane (per-q) softmax rescale + epilogue.
// (R4 resubmit: R3 bench never ran - GPU acquisition timeout.)
// ---------------------------------------------------------------------------

typedef __attribute__((ext_vector_type(8))) short bf16x8;
typedef __attribute__((ext_vector_type(4))) float f32x4;
typedef __attribute__((ext_vector_type(16))) float f32x16;
typedef __attribute__((ext_vector_type(4))) unsigned int u32x4;

// 1/sqrt(dh) * log2(e): folded into Q projection -> attention works in exp2 domain
#define QSCALE 0.18033688011112042f

__device__ __forceinline__ unsigned short f2b(float f) {
    unsigned int u = __float_as_uint(f);
    u += 0x7FFFu + ((u >> 16) & 1u);
    return (unsigned short)(u >> 16);
}

__device__ __forceinline__ unsigned cvt_pk_bf16(float lo, float hi) {
    unsigned r;
    asm("v_cvt_pk_bf16_f32 %0, %1, %2" : "=v"(r) : "v"(lo), "v"(hi));
    return r;
}

__device__ __forceinline__ float exp2a(float x) {
    float r;  // s_nop guards the TRANS->VALU hazard around inline asm
    asm("v_exp_f32 %0, %1\n\ts_nop 1" : "=v"(r) : "v"(x));
    return r;
}

__device__ __forceinline__ void gld_lds16(const void* g, void* l) {
    __builtin_amdgcn_global_load_lds(
        (const __attribute__((address_space(1))) unsigned int*)g,
        (__attribute__((address_space(3))) unsigned int*)l, 16, 0, 0);
}

// ---------------------------------------------------------------------------
// fp32 -> bf16 for the 3 inputs (z-batched). n4 per input = 4096*1024/4.
// ---------------------------------------------------------------------------
__global__ __launch_bounds__(256) void f32_to_bf16_3(
    const float* __restrict__ i0, const float* __restrict__ i1, const float* __restrict__ i2,
    unsigned short* __restrict__ o0, unsigned short* __restrict__ o1, unsigned short* __restrict__ o2)
{
    const int z = blockIdx.y;
    const float* in = z == 0 ? i0 : (z == 1 ? i1 : i2);
    unsigned short* out = z == 0 ? o0 : (z == 1 ? o1 : o2);
    int i = blockIdx.x * 256 + threadIdx.x;
    float4 v = ((const float4*)in)[i];
    ushort4 o;
    o.x = f2b(v.x); o.y = f2b(v.y); o.z = f2b(v.z); o.w = f2b(v.w);
    ((ushort4*)out)[i] = o;
}

// ---------------------------------------------------------------------------
// 4 weight transposes+converts (z-batched): out[c][r] = bf16(in[r][c]), 1024^2
// ---------------------------------------------------------------------------
__global__ __launch_bounds__(256) void transpose_w4(
    const float* __restrict__ W0, const float* __restrict__ W1,
    const float* __restrict__ W2, const float* __restrict__ W3,
    unsigned short* __restrict__ O0, unsigned short* __restrict__ O1,
    unsigned short* __restrict__ O2, unsigned short* __restrict__ O3)
{
    __shared__ unsigned short tile[32][33];
    const int z = blockIdx.z;
    const float* in = z == 0 ? W0 : z == 1 ? W1 : z == 2 ? W2 : W3;
    unsigned short* out = z == 0 ? O0 : z == 1 ? O1 : z == 2 ? O2 : O3;
    const int c0 = blockIdx.x * 32, r0 = blockIdx.y * 32;
    const int tx = threadIdx.x, ty = threadIdx.y;
#pragma unroll
    for (int i = 0; i < 4; ++i)
        tile[ty + i * 8][tx] = f2b(in[(size_t)(r0 + ty + i * 8) * 1024 + c0 + tx]);
    __syncthreads();
#pragma unroll
    for (int i = 0; i < 4; ++i)
        out[(size_t)(c0 + ty + i * 8) * 1024 + r0 + tx] = tile[tx][ty + i * 8];
}

// ---------------------------------------------------------------------------
// GEMM C = A[4096x1024] * Bt[1024x1024]^T, tile 128xBN, BK=32, 4 waves.
// MODE 1: z in {0,1,2} selects (A,Bt) and epilogue {Q row-major*QSCALE,
//         K packed image, V sigma-packed image}. MODE 0: fp32 row-major.
//
// K image (per bh, kvt; 4096 shorts): addr = T*2048 + ks*512 + hib*256 +
//   (kv&31)*8 + i  holds K[kv = 32T + (kv&31)][d = 16ks + 8hib + i]
// V image: addr = dt*2048 + kstep*512 + hib*256 + (d&31)*8 + i  holds
//   Vt[d][kv], kv = 32T + 8g + 4hib + (kv&3), kstep = 2T+(g>>1), i=(g&1)*4+(kv&3)
// ---------------------------------------------------------------------------
template <int BN, int MODE>
__global__ __launch_bounds__(256) void gemm_bt(
    const unsigned short* __restrict__ A0, const unsigned short* __restrict__ A1,
    const unsigned short* __restrict__ A2,
    const unsigned short* __restrict__ B0, const unsigned short* __restrict__ B1,
    const unsigned short* __restrict__ B2,
    void* __restrict__ Cq, void* __restrict__ Ck, void* __restrict__ Cv)
{
    constexpr int K = 1024, N = 1024;
    constexpr int NB = BN / 32;
    __shared__ unsigned short lds_a[128 * 32];
    __shared__ unsigned short lds_b[BN * 32];
    const int tid = threadIdx.x;
    const int wid = tid >> 6, ln = tid & 15, lg = (tid & 63) >> 4;
    const int z = (MODE == 1) ? blockIdx.z : 0;
    const unsigned short* A = (z == 0) ? A0 : (z == 1) ? A1 : A2;
    const unsigned short* Bt = (z == 0) ? B0 : (z == 1) ? B1 : B2;
    const int m0 = blockIdx.y * 128, n0 = blockIdx.x * BN;
    const int wr = wid >> 1, wc = wid & 1;

    f32x4 acc[4][NB];
#pragma unroll
    for (int m = 0; m < 4; ++m)
#pragma unroll
        for (int n = 0; n < NB; ++n) acc[m][n] = {};

    const int srow = tid >> 2, scol = (tid & 3) * 8;
    const unsigned short* ga = A + (size_t)(m0 + srow) * K + scol;
    const unsigned short* gb = Bt + (size_t)(n0 + srow) * K + scol;
    unsigned short* la = lds_a + wid * 512;
    unsigned short* lb = lds_b + wid * 512;

    for (int k0 = 0; k0 < K; k0 += 32) {
        gld_lds16(ga + k0, la);
        gld_lds16(ga + k0 + 64 * K, la + 2048);
        gld_lds16(gb + k0, lb);
        if constexpr (BN == 128) gld_lds16(gb + k0 + 64 * K, lb + 2048);
        __syncthreads();

        bf16x8 af[4], bfr[NB];
#pragma unroll
        for (int m = 0; m < 4; ++m)
            af[m] = *(const bf16x8*)&lds_a[(wr * 64 + m * 16 + ln) * 32 + lg * 8];
#pragma unroll
        for (int n = 0; n < NB; ++n)
            bfr[n] = *(const bf16x8*)&lds_b[(wc * (BN / 2) + n * 16 + ln) * 32 + lg * 8];
#pragma unroll
        for (int m = 0; m < 4; ++m)
#pragma unroll
            for (int n = 0; n < NB; ++n)
                acc[m][n] = __builtin_amdgcn_mfma_f32_16x16x32_bf16(af[m], bfr[n], acc[m][n], 0, 0, 0);
        __syncthreads();
    }

    const int gcb = n0 + wc * (BN / 2) + ln;
    const int grb = m0 + wr * 64 + lg * 4;

    if constexpr (MODE == 0) {
        float* C = (float*)Cq;
#pragma unroll
        for (int m = 0; m < 4; ++m)
#pragma unroll
            for (int n = 0; n < NB; ++n)
#pragma unroll
                for (int r = 0; r < 4; ++r)
                    C[(size_t)(grb + m * 16 + r) * N + gcb + n * 16] = acc[m][n][r];
    } else {
        if (z == 0) {  // Q: row-major bf16, pre-scaled into exp2 domain
            unsigned short* C = (unsigned short*)Cq;
#pragma unroll
            for (int m = 0; m < 4; ++m)
#pragma unroll
                for (int n = 0; n < NB; ++n)
#pragma unroll
                    for (int r = 0; r < 4; ++r)
                        C[(size_t)(grb + m * 16 + r) * N + gcb + n * 16] =
                            f2b(acc[m][n][r] * QSCALE);
        } else if (z == 1) {  // K packed
            unsigned short* Kp = (unsigned short*)Ck;
#pragma unroll
            for (int m = 0; m < 4; ++m)
#pragma unroll
                for (int n = 0; n < NB; ++n) {
                    int gr = grb + m * 16, gc = gcb + n * 16;
                    int bq = gr >> 11, kvg = gr & 2047, kvt = kvg >> 6;
                    int h = gc >> 6, d = gc & 63;
                    size_t img = ((size_t)(bq * 16 + h) * 32 + kvt) * 4096;
                    int ks = d >> 4, hib = (d >> 3) & 1, i = d & 7;
                    int kvb = kvg & 63, T = kvb >> 5;
                    size_t base = img + T * 2048 + ks * 512 + hib * 256 + i;
#pragma unroll
                    for (int r = 0; r < 4; ++r)
                        Kp[base + ((kvb & 31) + r) * 8] = f2b(acc[m][n][r]);
                }
        } else {  // V sigma-packed
            unsigned short* Vp = (unsigned short*)Cv;
#pragma unroll
            for (int m = 0; m < 4; ++m)
#pragma unroll
                for (int n = 0; n < NB; ++n) {
                    int gr = grb + m * 16, gc = gcb + n * 16;
                    int bq = gr >> 11, kvg = gr & 2047, kvt = kvg >> 6;
                    int h = gc >> 6, d = gc & 63;
                    size_t img = ((size_t)(bq * 16 + h) * 32 + kvt) * 4096;
                    int kvb = kvg & 63;
                    int T = kvb >> 5, g = (kvb >> 3) & 3, hib = (kvb >> 2) & 1;
                    int kstep = 2 * T + (g >> 1);
                    int dt = d >> 5, ln31 = d & 31;
                    size_t addr = img + dt * 2048 + kstep * 512 + hib * 256 + ln31 * 8 + (g & 1) * 4;
                    uint2 w;
                    w.x = cvt_pk_bf16(acc[m][n][0], acc[m][n][1]);
                    w.y = cvt_pk_bf16(acc[m][n][2], acc[m][n][3]);
                    *(uint2*)(Vp + addr) = w;
                }
        }
    }
}

// ---------------------------------------------------------------------------
// Flash attention, swapped-QK 32x32 MFMA. Block = 4 waves x 32 q-rows = 128 q.
// Grid 512 (16 q-blocks x 32 bh), XCD-swizzled. KV tile 64, double-buffered.
// Lane owns q = lane&31; hi = lane>>5 selects kv subset (+4*hi rows).
// ---------------------------------------------------------------------------
__global__ __launch_bounds__(256) void attn_kernel(
    const unsigned short* __restrict__ Qp,     // [4096][1024] bf16, * QSCALE
    const unsigned short* __restrict__ Kpack,  // [32 bh][32 kvt][4096]
    const unsigned short* __restrict__ Vpack,  // [32 bh][32 kvt][4096]
    unsigned short* __restrict__ Y)            // [4096][1024] bf16
{
    __shared__ unsigned short lds_k[2][4096];
    __shared__ unsigned short lds_v[2][4096];
    const int tid = threadIdx.x;
    const int wid = tid >> 6, lane = tid & 63;
    const int q31 = lane & 31, hi = lane >> 5;

    // XCD swizzle: 16 q-blocks sharing one bh land on the same XCD
    const int logical = (blockIdx.x & 7) * 64 + (blockIdx.x >> 3);
    const int bx = logical & 15, bh = logical >> 4;
    const int b = bh >> 4, h = bh & 15;
    const int tok0 = b * 2048;
    const int qw = bx * 128 + wid * 32;

    // Q B-fragments (col=q31, k = 16ks + 8hi + i), hoisted for all iters
    const unsigned short* qrow = Qp + (size_t)(tok0 + qw + q31) * 1024 + h * 64 + hi * 8;
    bf16x8 qf[4];
#pragma unroll
    for (int ks = 0; ks < 4; ++ks) qf[ks] = *(const bf16x8*)(qrow + ks * 16);

    const unsigned short* gk = Kpack + (size_t)bh * (32 * 4096);
    const unsigned short* gv = Vpack + (size_t)bh * (32 * 4096);

    float m_run = -1e30f, l_run = 0.f;
    f32x16 o[2] = {{}, {}};

    auto stage = [&](int buf, int kvt) {
#pragma unroll
        for (int c = 0; c < 2; ++c) {
            int m = c * 4 + wid;
            gld_lds16(gk + (size_t)kvt * 4096 + m * 512 + lane * 8, &lds_k[buf][m * 512]);
            gld_lds16(gv + (size_t)kvt * 4096 + m * 512 + lane * 8, &lds_v[buf][m * 512]);
        }
    };

    stage(0, 0);
    __syncthreads();

    for (int kvt = 0; kvt < 32; ++kvt) {
        const int buf = kvt & 1;
        if (kvt < 31) stage(buf ^ 1, kvt + 1);  // async prefetch overlaps compute

        // S^T = K_tile x Q^T : st[T][r] = S[q=q31][kv = 32T + (r&3) + 8(r>>2) + 4hi]
        f32x16 st[2];
#pragma unroll
        for (int T = 0; T < 2; ++T) {
            f32x16 zacc = {};
#pragma unroll
            for (int ks = 0; ks < 4; ++ks) {
                bf16x8 ka = *(const bf16x8*)&lds_k[buf][T * 2048 + ks * 512 + lane * 8];
                zacc = __builtin_amdgcn_mfma_f32_32x32x16_bf16(ka, qf[ks], zacc, 0, 0, 0);
            }
            st[T] = zacc;
        }

        // online softmax (exp2 domain), in-lane + one cross-half swap
        float pm = st[0][0];
#pragma unroll
        for (int r = 1; r < 16; ++r) pm = fmaxf(pm, st[0][r]);
#pragma unroll
        for (int r = 0; r < 16; ++r) pm = fmaxf(pm, st[1][r]);
        pm = fmaxf(pm, __shfl_xor(pm, 32));
        const float mn = fmaxf(m_run, pm);
        const float alpha = exp2a(m_run - mn);
        m_run = mn;

        float rs = 0.f;
        unsigned pk[2][8];
#pragma unroll
        for (int T = 0; T < 2; ++T)
#pragma unroll
            for (int g = 0; g < 4; ++g) {
                float p0 = exp2a(st[T][g * 4 + 0] - mn);
                float p1 = exp2a(st[T][g * 4 + 1] - mn);
                float p2 = exp2a(st[T][g * 4 + 2] - mn);
                float p3 = exp2a(st[T][g * 4 + 3] - mn);
                rs += (p0 + p1) + (p2 + p3);
                pk[T][g * 2 + 0] = cvt_pk_bf16(p0, p1);
                pk[T][g * 2 + 1] = cvt_pk_bf16(p2, p3);
            }
        rs += __shfl_xor(rs, 32);
        l_run = l_run * alpha + rs;

#pragma unroll
        for (int r = 0; r < 16; ++r) { o[0][r] *= alpha; o[1][r] *= alpha; }

        // PV: O^T = Vt x P^T.  A = V-fragment (rows = d), B = P-fragment
        // (cols = q) -- D col = lane&31 = q, D row = (r&3)+8(r>>2)+4hi = d.
        // (R2 bug: arguments were swapped.)
#pragma unroll
        for (int dt = 0; dt < 2; ++dt)
#pragma unroll
            for (int kstep = 0; kstep < 4; ++kstep) {
                bf16x8 va = *(const bf16x8*)&lds_v[buf][dt * 2048 + kstep * 512 + lane * 8];
                u32x4 w = {pk[kstep >> 1][4 * (kstep & 1) + 0], pk[kstep >> 1][4 * (kstep & 1) + 1],
                           pk[kstep >> 1][4 * (kstep & 1) + 2], pk[kstep >> 1][4 * (kstep & 1) + 3]};
                o[dt] = __builtin_amdgcn_mfma_f32_32x32x16_bf16(
                    va, __builtin_bit_cast(bf16x8, w), o[dt], 0, 0, 0);
            }
        __syncthreads();
    }

    // epilogue: d = 32dt + 8g + 4hi + rr, row = q
    const float inv = __builtin_amdgcn_rcpf(l_run);
    unsigned short* yout = Y + (size_t)(tok0 + qw + q31) * 1024 + h * 64 + hi * 4;
#pragma unroll
    for (int dt = 0; dt < 2; ++dt)
#pragma unroll
        for (int g = 0; g < 4; ++g) {
            uint2 w;
            w.x = cvt_pk_bf16(o[dt][g * 4 + 0] * inv, o[dt][g * 4 + 1] * inv);
            w.y = cvt_pk_bf16(o[dt][g * 4 + 2] * inv, o[dt][g * 4 + 3] * inv);
            *(uint2*)(yout + dt * 32 + g * 8) = w;
        }
}

// ---------------------------------------------------------------------------
extern "C" void kernel_launch(void* const* d_in, const int* in_sizes, int n_in,
                              void* d_out, int out_size, void* d_ws, size_t ws_size,
                              hipStream_t stream)
{
    const float* q_f = (const float*)d_in[0];
    const float* k_f = (const float*)d_in[1];
    const float* v_f = (const float*)d_in[2];
    const float* Wq  = (const float*)d_in[3];
    const float* Wk  = (const float*)d_in[4];
    const float* Wv  = (const float*)d_in[5];
    const float* Wo  = (const float*)d_in[6];
    float* out = (float*)d_out;

    const size_t X = (size_t)4096 * 1024;
    const size_t W = (size_t)1024 * 1024;
    unsigned short* ws  = (unsigned short*)d_ws;
    unsigned short* qb  = ws;
    unsigned short* kb  = qb + X;
    unsigned short* vb  = kb + X;
    unsigned short* wqt = vb + X;
    unsigned short* wkt = wqt + W;
    unsigned short* wvt = wkt + W;
    unsigned short* wot = wvt + W;
    unsigned short* Qp  = wot + W;
    unsigned short* Kpk = Qp + X;
    unsigned short* Vpk = Kpk + X;
    unsigned short* Yb  = Vpk + X;

    f32_to_bf16_3<<<dim3(4096, 3), 256, 0, stream>>>(q_f, k_f, v_f, qb, kb, vb);
    transpose_w4<<<dim3(32, 32, 4), dim3(32, 8), 0, stream>>>(Wq, Wk, Wv, Wo,
                                                              wqt, wkt, wvt, wot);
    // projections: Q -> row-major (scaled), K/V -> packed attention images
    gemm_bt<128, 1><<<dim3(8, 32, 3), 256, 0, stream>>>(qb, kb, vb, wqt, wkt, wvt,
                                                        Qp, Kpk, Vpk);
    attn_kernel<<<512, 256, 0, stream>>>(Qp, Kpk, Vpk, Yb);
    // output projection (fp32 out), 128x64 tiles for 2 blocks/CU
    gemm_bt<64, 0><<<dim3(16, 32, 1), 256, 0, stream>>>(Yb, nullptr, nullptr,
                                                        wot, nullptr, nullptr,
                                                        out, nullptr, nullptr);
}

// Round 5
// 238.728 us; speedup vs baseline: 1.4943x; 1.0468x over previous
//
#include <hip/hip_runtime.h>
#include <hip/hip_bf16.h>

// ---------------------------------------------------------------------------
// MHA B=2,S=2048,D=1024,H=16,dh=64 (fp32 in/out), bf16 MFMA pipeline.
// R5: (a) attn -> 2-wave/128-thread blocks, grid 1024 (4 indep blocks/CU);
//     (b) exp via __builtin_amdgcn_exp2f (no inline-asm scheduling fence);
//     (c) GEMM -> double-buffered LDS, prefetch-before-compute, 1 barrier/iter.
// ---------------------------------------------------------------------------

typedef __attribute__((ext_vector_type(8))) short bf16x8;
typedef __attribute__((ext_vector_type(4))) float f32x4;
typedef __attribute__((ext_vector_type(16))) float f32x16;
typedef __attribute__((ext_vector_type(4))) unsigned int u32x4;

// 1/sqrt(dh) * log2(e): folded into Q projection -> attention works in exp2 domain
#define QSCALE 0.18033688011112042f

__device__ __forceinline__ unsigned short f2b(float f) {
    unsigned int u = __float_as_uint(f);
    u += 0x7FFFu + ((u >> 16) & 1u);
    return (unsigned short)(u >> 16);
}

__device__ __forceinline__ unsigned cvt_pk_bf16(float lo, float hi) {
    unsigned r;
    asm("v_cvt_pk_bf16_f32 %0, %1, %2" : "=v"(r) : "v"(lo), "v"(hi));
    return r;
}

__device__ __forceinline__ void gld_lds16(const void* g, void* l) {
    __builtin_amdgcn_global_load_lds(
        (const __attribute__((address_space(1))) unsigned int*)g,
        (__attribute__((address_space(3))) unsigned int*)l, 16, 0, 0);
}

// ---------------------------------------------------------------------------
// fp32 -> bf16 for the 3 inputs (z-batched). n4 per input = 4096*1024/4.
// ---------------------------------------------------------------------------
__global__ __launch_bounds__(256) void f32_to_bf16_3(
    const float* __restrict__ i0, const float* __restrict__ i1, const float* __restrict__ i2,
    unsigned short* __restrict__ o0, unsigned short* __restrict__ o1, unsigned short* __restrict__ o2)
{
    const int z = blockIdx.y;
    const float* in = z == 0 ? i0 : (z == 1 ? i1 : i2);
    unsigned short* out = z == 0 ? o0 : (z == 1 ? o1 : o2);
    int i = blockIdx.x * 256 + threadIdx.x;
    float4 v = ((const float4*)in)[i];
    ushort4 o;
    o.x = f2b(v.x); o.y = f2b(v.y); o.z = f2b(v.z); o.w = f2b(v.w);
    ((ushort4*)out)[i] = o;
}

// ---------------------------------------------------------------------------
// 4 weight transposes+converts (z-batched): out[c][r] = bf16(in[r][c]), 1024^2
// ---------------------------------------------------------------------------
__global__ __launch_bounds__(256) void transpose_w4(
    const float* __restrict__ W0, const float* __restrict__ W1,
    const float* __restrict__ W2, const float* __restrict__ W3,
    unsigned short* __restrict__ O0, unsigned short* __restrict__ O1,
    unsigned short* __restrict__ O2, unsigned short* __restrict__ O3)
{
    __shared__ unsigned short tile[32][33];
    const int z = blockIdx.z;
    const float* in = z == 0 ? W0 : z == 1 ? W1 : z == 2 ? W2 : W3;
    unsigned short* out = z == 0 ? O0 : z == 1 ? O1 : z == 2 ? O2 : O3;
    const int c0 = blockIdx.x * 32, r0 = blockIdx.y * 32;
    const int tx = threadIdx.x, ty = threadIdx.y;
#pragma unroll
    for (int i = 0; i < 4; ++i)
        tile[ty + i * 8][tx] = f2b(in[(size_t)(r0 + ty + i * 8) * 1024 + c0 + tx]);
    __syncthreads();
#pragma unroll
    for (int i = 0; i < 4; ++i)
        out[(size_t)(c0 + ty + i * 8) * 1024 + r0 + tx] = tile[tx][ty + i * 8];
}

// ---------------------------------------------------------------------------
// GEMM C = A[4096x1024] * Bt[1024x1024]^T, tile 128xBN, BK=32, 4 waves.
// Double-buffered LDS: prefetch tile k+1 (async global->LDS) is issued BEFORE
// computing tile k; single __syncthreads per iter drains vmcnt + covers reads.
// MODE 1: z in {0,1,2} selects (A,Bt) and epilogue {Q row-major*QSCALE,
//         K packed image, V sigma-packed image}. MODE 0: fp32 row-major.
//
// K image (per bh, kvt; 4096 shorts): addr = T*2048 + ks*512 + hib*256 +
//   (kv&31)*8 + i  holds K[kv = 32T + (kv&31)][d = 16ks + 8hib + i]
// V image: addr = dt*2048 + kstep*512 + hib*256 + (d&31)*8 + i  holds
//   Vt[d][kv], kv = 32T + 8g + 4hib + (kv&3), kstep = 2T+(g>>1), i=(g&1)*4+(kv&3)
// ---------------------------------------------------------------------------
template <int BN, int MODE>
__global__ __launch_bounds__(256) void gemm_bt(
    const unsigned short* __restrict__ A0, const unsigned short* __restrict__ A1,
    const unsigned short* __restrict__ A2,
    const unsigned short* __restrict__ B0, const unsigned short* __restrict__ B1,
    const unsigned short* __restrict__ B2,
    void* __restrict__ Cq, void* __restrict__ Ck, void* __restrict__ Cv)
{
    constexpr int K = 1024, N = 1024;
    constexpr int NB = BN / 32;
    __shared__ unsigned short lds_a[2][128 * 32];
    __shared__ unsigned short lds_b[2][BN * 32];
    const int tid = threadIdx.x;
    const int wid = tid >> 6, ln = tid & 15, lg = (tid & 63) >> 4;
    const int z = (MODE == 1) ? blockIdx.z : 0;
    const unsigned short* A = (z == 0) ? A0 : (z == 1) ? A1 : A2;
    const unsigned short* Bt = (z == 0) ? B0 : (z == 1) ? B1 : B2;
    const int m0 = blockIdx.y * 128, n0 = blockIdx.x * BN;
    const int wr = wid >> 1, wc = wid & 1;

    f32x4 acc[4][NB];
#pragma unroll
    for (int m = 0; m < 4; ++m)
#pragma unroll
        for (int n = 0; n < NB; ++n) acc[m][n] = {};

    const unsigned short* ga = A + (size_t)(m0 + (tid >> 2)) * K + (tid & 3) * 8;
    const unsigned short* gb = Bt + (size_t)(n0 + (tid >> 2)) * K + (tid & 3) * 8;

    auto stage = [&](int buf, int k0) {
        gld_lds16(ga + k0, &lds_a[buf][wid * 512]);
        gld_lds16(ga + k0 + 64 * K, &lds_a[buf][wid * 512 + 2048]);
        gld_lds16(gb + k0, &lds_b[buf][wid * 512]);
        if constexpr (BN == 128) gld_lds16(gb + k0 + 64 * K, &lds_b[buf][wid * 512 + 2048]);
    };

    stage(0, 0);
    __syncthreads();

    for (int k0 = 0; k0 < K; k0 += 32) {
        const int buf = (k0 >> 5) & 1;
        if (k0 + 32 < K) stage(buf ^ 1, k0 + 32);   // async prefetch next tile

        bf16x8 af[4], bfr[NB];
#pragma unroll
        for (int m = 0; m < 4; ++m)
            af[m] = *(const bf16x8*)&lds_a[buf][(wr * 64 + m * 16 + ln) * 32 + lg * 8];
#pragma unroll
        for (int n = 0; n < NB; ++n)
            bfr[n] = *(const bf16x8*)&lds_b[buf][(wc * (BN / 2) + n * 16 + ln) * 32 + lg * 8];
#pragma unroll
        for (int m = 0; m < 4; ++m)
#pragma unroll
            for (int n = 0; n < NB; ++n)
                acc[m][n] = __builtin_amdgcn_mfma_f32_16x16x32_bf16(af[m], bfr[n], acc[m][n], 0, 0, 0);
        __syncthreads();   // reads of buf done + prefetch into buf^1 landed
    }

    const int gcb = n0 + wc * (BN / 2) + ln;
    const int grb = m0 + wr * 64 + lg * 4;

    if constexpr (MODE == 0) {
        float* C = (float*)Cq;
#pragma unroll
        for (int m = 0; m < 4; ++m)
#pragma unroll
            for (int n = 0; n < NB; ++n)
#pragma unroll
                for (int r = 0; r < 4; ++r)
                    C[(size_t)(grb + m * 16 + r) * N + gcb + n * 16] = acc[m][n][r];
    } else {
        if (z == 0) {  // Q: row-major bf16, pre-scaled into exp2 domain
            unsigned short* C = (unsigned short*)Cq;
#pragma unroll
            for (int m = 0; m < 4; ++m)
#pragma unroll
                for (int n = 0; n < NB; ++n)
#pragma unroll
                    for (int r = 0; r < 4; ++r)
                        C[(size_t)(grb + m * 16 + r) * N + gcb + n * 16] =
                            f2b(acc[m][n][r] * QSCALE);
        } else if (z == 1) {  // K packed
            unsigned short* Kp = (unsigned short*)Ck;
#pragma unroll
            for (int m = 0; m < 4; ++m)
#pragma unroll
                for (int n = 0; n < NB; ++n) {
                    int gr = grb + m * 16, gc = gcb + n * 16;
                    int bq = gr >> 11, kvg = gr & 2047, kvt = kvg >> 6;
                    int h = gc >> 6, d = gc & 63;
                    size_t img = ((size_t)(bq * 16 + h) * 32 + kvt) * 4096;
                    int ks = d >> 4, hib = (d >> 3) & 1, i = d & 7;
                    int kvb = kvg & 63, T = kvb >> 5;
                    size_t base = img + T * 2048 + ks * 512 + hib * 256 + i;
#pragma unroll
                    for (int r = 0; r < 4; ++r)
                        Kp[base + ((kvb & 31) + r) * 8] = f2b(acc[m][n][r]);
                }
        } else {  // V sigma-packed
            unsigned short* Vp = (unsigned short*)Cv;
#pragma unroll
            for (int m = 0; m < 4; ++m)
#pragma unroll
                for (int n = 0; n < NB; ++n) {
                    int gr = grb + m * 16, gc = gcb + n * 16;
                    int bq = gr >> 11, kvg = gr & 2047, kvt = kvg >> 6;
                    int h = gc >> 6, d = gc & 63;
                    size_t img = ((size_t)(bq * 16 + h) * 32 + kvt) * 4096;
                    int kvb = kvg & 63;
                    int T = kvb >> 5, g = (kvb >> 3) & 3, hib = (kvb >> 2) & 1;
                    int kstep = 2 * T + (g >> 1);
                    int dt = d >> 5, ln31 = d & 31;
                    size_t addr = img + dt * 2048 + kstep * 512 + hib * 256 + ln31 * 8 + (g & 1) * 4;
                    uint2 w;
                    w.x = cvt_pk_bf16(acc[m][n][0], acc[m][n][1]);
                    w.y = cvt_pk_bf16(acc[m][n][2], acc[m][n][3]);
                    *(uint2*)(Vp + addr) = w;
                }
        }
    }
}

// ---------------------------------------------------------------------------
// Flash attention, swapped-QK 32x32 MFMA. Block = 2 waves x 32 q-rows = 64 q.
// Grid 1024 (32 q-blocks x 32 bh), XCD-swizzled -> 4 independent blocks/CU.
// KV tile 64, double-buffered. Lane owns q = lane&31; hi = lane>>5.
// ---------------------------------------------------------------------------
__global__ __launch_bounds__(128) void attn_kernel(
    const unsigned short* __restrict__ Qp,     // [4096][1024] bf16, * QSCALE
    const unsigned short* __restrict__ Kpack,  // [32 bh][32 kvt][4096]
    const unsigned short* __restrict__ Vpack,  // [32 bh][32 kvt][4096]
    unsigned short* __restrict__ Y)            // [4096][1024] bf16
{
    __shared__ unsigned short lds_k[2][4096];
    __shared__ unsigned short lds_v[2][4096];
    const int tid = threadIdx.x;
    const int wid = tid >> 6, lane = tid & 63;
    const int q31 = lane & 31, hi = lane >> 5;

    // XCD swizzle (1024 % 8 == 0, bijective): 32 q-blocks of one bh per XCD
    const int logical = (blockIdx.x & 7) * 128 + (blockIdx.x >> 3);
    const int bx = logical & 31, bh = logical >> 5;
    const int b = bh >> 4, h = bh & 15;
    const int tok0 = b * 2048;
    const int qw = bx * 64 + wid * 32;

    // Q B-fragments (col=q31, k = 16ks + 8hi + i), hoisted for all iters
    const unsigned short* qrow = Qp + (size_t)(tok0 + qw + q31) * 1024 + h * 64 + hi * 8;
    bf16x8 qf[4];
#pragma unroll
    for (int ks = 0; ks < 4; ++ks) qf[ks] = *(const bf16x8*)(qrow + ks * 16);

    const unsigned short* gk = Kpack + (size_t)bh * (32 * 4096);
    const unsigned short* gv = Vpack + (size_t)bh * (32 * 4096);

    float m_run = -1e30f, l_run = 0.f;
    f32x16 o[2] = {{}, {}};

    auto stage = [&](int buf, int kvt) {
#pragma unroll
        for (int c = 0; c < 4; ++c) {
            int m = c * 2 + wid;   // 2 waves cover segments 0..7
            gld_lds16(gk + (size_t)kvt * 4096 + m * 512 + lane * 8, &lds_k[buf][m * 512]);
            gld_lds16(gv + (size_t)kvt * 4096 + m * 512 + lane * 8, &lds_v[buf][m * 512]);
        }
    };

    stage(0, 0);
    __syncthreads();

    for (int kvt = 0; kvt < 32; ++kvt) {
        const int buf = kvt & 1;
        if (kvt < 31) stage(buf ^ 1, kvt + 1);  // async prefetch overlaps compute

        // S^T = K_tile x Q^T : st[T][r] = S[q=q31][kv = 32T + (r&3) + 8(r>>2) + 4hi]
        f32x16 st[2];
#pragma unroll
        for (int T = 0; T < 2; ++T) {
            f32x16 zacc = {};
#pragma unroll
            for (int ks = 0; ks < 4; ++ks) {
                bf16x8 ka = *(const bf16x8*)&lds_k[buf][T * 2048 + ks * 512 + lane * 8];
                zacc = __builtin_amdgcn_mfma_f32_32x32x16_bf16(ka, qf[ks], zacc, 0, 0, 0);
            }
            st[T] = zacc;
        }

        // online softmax (exp2 domain), in-lane + one cross-half swap
        float pm = st[0][0];
#pragma unroll
        for (int r = 1; r < 16; ++r) pm = fmaxf(pm, st[0][r]);
#pragma unroll
        for (int r = 0; r < 16; ++r) pm = fmaxf(pm, st[1][r]);
        pm = fmaxf(pm, __shfl_xor(pm, 32));
        const float mn = fmaxf(m_run, pm);
        const float alpha = __builtin_amdgcn_exp2f(m_run - mn);
        m_run = mn;

        float rs = 0.f;
        unsigned pk[2][8];
#pragma unroll
        for (int T = 0; T < 2; ++T)
#pragma unroll
            for (int g = 0; g < 4; ++g) {
                float p0 = __builtin_amdgcn_exp2f(st[T][g * 4 + 0] - mn);
                float p1 = __builtin_amdgcn_exp2f(st[T][g * 4 + 1] - mn);
                float p2 = __builtin_amdgcn_exp2f(st[T][g * 4 + 2] - mn);
                float p3 = __builtin_amdgcn_exp2f(st[T][g * 4 + 3] - mn);
                rs += (p0 + p1) + (p2 + p3);
                pk[T][g * 2 + 0] = cvt_pk_bf16(p0, p1);
                pk[T][g * 2 + 1] = cvt_pk_bf16(p2, p3);
            }
        rs += __shfl_xor(rs, 32);
        l_run = l_run * alpha + rs;

#pragma unroll
        for (int r = 0; r < 16; ++r) { o[0][r] *= alpha; o[1][r] *= alpha; }

        // PV: O^T = Vt x P^T.  A = V-fragment (rows = d), B = P-fragment
        // (cols = q) -- D col = lane&31 = q, D row = (r&3)+8(r>>2)+4hi = d.
#pragma unroll
        for (int dt = 0; dt < 2; ++dt)
#pragma unroll
            for (int kstep = 0; kstep < 4; ++kstep) {
                bf16x8 va = *(const bf16x8*)&lds_v[buf][dt * 2048 + kstep * 512 + lane * 8];
                u32x4 w = {pk[kstep >> 1][4 * (kstep & 1) + 0], pk[kstep >> 1][4 * (kstep & 1) + 1],
                           pk[kstep >> 1][4 * (kstep & 1) + 2], pk[kstep >> 1][4 * (kstep & 1) + 3]};
                o[dt] = __builtin_amdgcn_mfma_f32_32x32x16_bf16(
                    va, __builtin_bit_cast(bf16x8, w), o[dt], 0, 0, 0);
            }
        __syncthreads();
    }

    // epilogue: d = 32dt + 8g + 4hi + rr, row = q
    const float inv = __builtin_amdgcn_rcpf(l_run);
    unsigned short* yout = Y + (size_t)(tok0 + qw + q31) * 1024 + h * 64 + hi * 4;
#pragma unroll
    for (int dt = 0; dt < 2; ++dt)
#pragma unroll
        for (int g = 0; g < 4; ++g) {
            uint2 w;
            w.x = cvt_pk_bf16(o[dt][g * 4 + 0] * inv, o[dt][g * 4 + 1] * inv);
            w.y = cvt_pk_bf16(o[dt][g * 4 + 2] * inv, o[dt][g * 4 + 3] * inv);
            *(uint2*)(yout + dt * 32 + g * 8) = w;
        }
}

// ---------------------------------------------------------------------------
extern "C" void kernel_launch(void* const* d_in, const int* in_sizes, int n_in,
                              void* d_out, int out_size, void* d_ws, size_t ws_size,
                              hipStream_t stream)
{
    const float* q_f = (const float*)d_in[0];
    const float* k_f = (const float*)d_in[1];
    const float* v_f = (const float*)d_in[2];
    const float* Wq  = (const float*)d_in[3];
    const float* Wk  = (const float*)d_in[4];
    const float* Wv  = (const float*)d_in[5];
    const float* Wo  = (const float*)d_in[6];
    float* out = (float*)d_out;

    const size_t X = (size_t)4096 * 1024;
    const size_t W = (size_t)1024 * 1024;
    unsigned short* ws  = (unsigned short*)d_ws;
    unsigned short* qb  = ws;
    unsigned short* kb  = qb + X;
    unsigned short* vb  = kb + X;
    unsigned short* wqt = vb + X;
    unsigned short* wkt = wqt + W;
    unsigned short* wvt = wkt + W;
    unsigned short* wot = wvt + W;
    unsigned short* Qp  = wot + W;
    unsigned short* Kpk = Qp + X;
    unsigned short* Vpk = Kpk + X;
    unsigned short* Yb  = Vpk + X;

    f32_to_bf16_3<<<dim3(4096, 3), 256, 0, stream>>>(q_f, k_f, v_f, qb, kb, vb);
    transpose_w4<<<dim3(32, 32, 4), dim3(32, 8), 0, stream>>>(Wq, Wk, Wv, Wo,
                                                              wqt, wkt, wvt, wot);
    // projections: Q -> row-major (scaled), K/V -> packed attention images
    gemm_bt<128, 1><<<dim3(8, 32, 3), 256, 0, stream>>>(qb, kb, vb, wqt, wkt, wvt,
                                                        Qp, Kpk, Vpk);
    attn_kernel<<<1024, 128, 0, stream>>>(Qp, Kpk, Vpk, Yb);
    // output projection (fp32 out), 128x64 tiles for 2 blocks/CU
    gemm_bt<64, 0><<<dim3(16, 32, 1), 256, 0, stream>>>(Yb, nullptr, nullptr,
                                                        wot, nullptr, nullptr,
                                                        out, nullptr, nullptr);
}